// Round 2
// baseline (72371.747 us; speedup 1.0000x reference)
//
#include <hip/hip_runtime.h>

// Kernel ridge regression, RBF kernel. N=M=8192, D=32, gamma=1/32, reg=1e-3.
// CG solve, fixed iteration count, all scalars device-side in per-iteration
// slot arrays (graph-capture-safe). Two paths picked by ws_size at capture:
//   A) ws >= 257MB: materialize K fp32 (256MB), matvec reads it (~41us).
//   B) else:        matrix-free matvec recomputing the gram on the fly.
// Output: fused on-the-fly K_test @ alpha (K_test never materialized).

#define NN 8192
#define DD 32
#define GAMMA 0.03125f
#define REGL 1e-3f
#define NITER 160
#define NSLOT 64

__device__ __forceinline__ double bfly_sum_d(double v) {
#pragma unroll
  for (int off = 1; off < 64; off <<= 1) v += __shfl_xor(v, off, 64);
  return v;
}

__device__ __forceinline__ double wave_down_sum_d(double v) {
#pragma unroll
  for (int off = 32; off > 0; off >>= 1) v += __shfl_down(v, off, 64);
  return v;
}

// ---------------- init ----------------

__global__ void zero_accum(double* __restrict__ buf, int n) {
  int stride = gridDim.x * blockDim.x;
  for (int i = blockIdx.x * blockDim.x + threadIdx.x; i < n; i += stride)
    buf[i] = 0.0;
}

__global__ void row_norms(const float* __restrict__ X, float* __restrict__ xx) {
  int i = blockIdx.x * blockDim.x + threadIdx.x;
  if (i < NN) {
    const float4* row = (const float4*)(X + (size_t)i * DD);
    float s = 0.f;
#pragma unroll
    for (int k = 0; k < DD / 4; ++k) {
      float4 v = row[k];
      s += v.x * v.x + v.y * v.y + v.z * v.z + v.w * v.w;
    }
    xx[i] = s;
  }
}

__global__ void cg_init(const float* __restrict__ y, float* __restrict__ x,
                        float* __restrict__ r, float* __restrict__ p,
                        double* __restrict__ rho0) {
  double acc = 0.0;
  int stride = gridDim.x * blockDim.x;
  for (int i = blockIdx.x * blockDim.x + threadIdx.x; i < NN; i += stride) {
    float v = y[i];
    x[i] = 0.f;
    r[i] = v;
    p[i] = v;
    acc += (double)v * (double)v;
  }
  __shared__ double sred[4];
  acc = wave_down_sum_d(acc);
  if ((threadIdx.x & 63) == 0) sred[threadIdx.x >> 6] = acc;
  __syncthreads();
  if (threadIdx.x == 0) rho0[blockIdx.x] = sred[0] + sred[1] + sred[2] + sred[3];
}

// ---------------- gram build (path A) ----------------

__global__ __launch_bounds__(256) void build_K(const float* __restrict__ X,
                                               const float* __restrict__ xx,
                                               float* __restrict__ K) {
  __shared__ float As[64][36];
  __shared__ float Bs[64][36];
  int i0 = blockIdx.y * 64, j0 = blockIdx.x * 64;
  int tid = threadIdx.x;
  for (int t = tid; t < 64 * 32; t += 256) {
    int rr = t >> 5, cc = t & 31;
    As[rr][cc] = X[(size_t)(i0 + rr) * DD + cc];
    Bs[rr][cc] = X[(size_t)(j0 + rr) * DD + cc];
  }
  __syncthreads();
  int tx = tid & 15, ty = tid >> 4;
  float acc[4][4] = {};
#pragma unroll
  for (int k = 0; k < 32; k += 4) {
    float4 a[4], b[4];
#pragma unroll
    for (int u = 0; u < 4; ++u) a[u] = *(const float4*)&As[ty * 4 + u][k];
#pragma unroll
    for (int v = 0; v < 4; ++v) b[v] = *(const float4*)&Bs[tx * 4 + v][k];
#pragma unroll
    for (int u = 0; u < 4; ++u)
#pragma unroll
      for (int v = 0; v < 4; ++v)
        acc[u][v] += a[u].x * b[v].x + a[u].y * b[v].y + a[u].z * b[v].z +
                     a[u].w * b[v].w;
  }
#pragma unroll
  for (int u = 0; u < 4; ++u) {
    int gi = i0 + ty * 4 + u;
    float xxi = xx[gi];
    float4 out;
    float* o = (float*)&out;
#pragma unroll
    for (int v = 0; v < 4; ++v) {
      int gj = j0 + tx * 4 + v;
      float sq = fmaxf(xxi + xx[gj] - 2.0f * acc[u][v], 0.0f);
      o[v] = expf(-GAMMA * sq);
    }
    *(float4*)&K[(size_t)gi * NN + j0 + tx * 4] = out;
  }
}

// ---------------- matvec, path A: read materialized K ----------------

__global__ __launch_bounds__(256) void matvec(const float* __restrict__ K,
                                              const float* __restrict__ p,
                                              float* __restrict__ q,
                                              double* __restrict__ pq_slots) {
  int row = blockIdx.x;
  const float4* Kr = (const float4*)(K + (size_t)row * NN);
  const float4* p4 = (const float4*)p;
  float acc = 0.f;
#pragma unroll
  for (int it = 0; it < NN / 4 / 256; ++it) {
    int c = threadIdx.x + it * 256;
    float4 kv = Kr[c];
    float4 pv = p4[c];
    acc += kv.x * pv.x + kv.y * pv.y + kv.z * pv.z + kv.w * pv.w;
  }
  double v = wave_down_sum_d((double)acc);
  __shared__ double sred[4];
  if ((threadIdx.x & 63) == 0) sred[threadIdx.x >> 6] = v;
  __syncthreads();
  if (threadIdx.x == 0) {
    double tot = sred[0] + sred[1] + sred[2] + sred[3];
    double pr = (double)p[row];
    double qv = tot + (double)REGL * pr;
    q[row] = (float)qv;
    atomicAdd(&pq_slots[row & (NSLOT - 1)], qv * pr);
  }
}

// ---------------- matvec, path B: matrix-free, gram recomputed ----------------
// One block per 64 rows; iterate col tiles of 64: compute gram tile, fuse
// multiply by p and accumulate per-row in fp64.

__global__ __launch_bounds__(256) void matvec_free(
    const float* __restrict__ X, const float* __restrict__ xx,
    const float* __restrict__ p, float* __restrict__ q,
    double* __restrict__ pq_slots) {
  __shared__ float As[64][36];
  __shared__ float Bs[64][36];
  __shared__ float pj[64];
  __shared__ float xxB[64];
  __shared__ double red[64][17];
  int i0 = blockIdx.x * 64;
  int tid = threadIdx.x;
  for (int t = tid; t < 64 * 32; t += 256) {
    int rr = t >> 5, cc = t & 31;
    As[rr][cc] = X[(size_t)(i0 + rr) * DD + cc];
  }
  int tx = tid & 15, ty = tid >> 4;
  float xxA[4];
#pragma unroll
  for (int u = 0; u < 4; ++u) xxA[u] = xx[i0 + ty * 4 + u];
  double accq[4] = {0.0, 0.0, 0.0, 0.0};
  for (int j0 = 0; j0 < NN; j0 += 64) {
    __syncthreads();
    for (int t = tid; t < 64 * 32; t += 256) {
      int rr = t >> 5, cc = t & 31;
      Bs[rr][cc] = X[(size_t)(j0 + rr) * DD + cc];
    }
    if (tid < 64) {
      pj[tid] = p[j0 + tid];
      xxB[tid] = xx[j0 + tid];
    }
    __syncthreads();
    float dot[4][4] = {};
#pragma unroll
    for (int k = 0; k < 32; k += 4) {
      float4 a[4], b[4];
#pragma unroll
      for (int u = 0; u < 4; ++u) a[u] = *(const float4*)&As[ty * 4 + u][k];
#pragma unroll
      for (int v = 0; v < 4; ++v) b[v] = *(const float4*)&Bs[tx * 4 + v][k];
#pragma unroll
      for (int u = 0; u < 4; ++u)
#pragma unroll
        for (int v = 0; v < 4; ++v)
          dot[u][v] += a[u].x * b[v].x + a[u].y * b[v].y + a[u].z * b[v].z +
                       a[u].w * b[v].w;
    }
#pragma unroll
    for (int v = 0; v < 4; ++v) {
      float xxb = xxB[tx * 4 + v];
      float pv = pj[tx * 4 + v];
#pragma unroll
      for (int u = 0; u < 4; ++u) {
        float sq = fmaxf(xxA[u] + xxb - 2.0f * dot[u][v], 0.0f);
        accq[u] += (double)(expf(-GAMMA * sq) * pv);
      }
    }
  }
  __syncthreads();
#pragma unroll
  for (int u = 0; u < 4; ++u) red[ty * 4 + u][tx] = accq[u];
  __syncthreads();
  if (tid < 64) {
    double s = 0.0;
#pragma unroll
    for (int t = 0; t < 16; ++t) s += red[tid][t];
    double pr = (double)p[i0 + tid];
    double qv = s + (double)REGL * pr;
    q[i0 + tid] = (float)qv;
    double c = bfly_sum_d(qv * pr);
    if (tid == 0) atomicAdd(&pq_slots[blockIdx.x & (NSLOT - 1)], c);
  }
}

// ---------------- CG scalar/vector updates ----------------

__global__ __launch_bounds__(256) void cg_update(
    float* __restrict__ x, float* __restrict__ r, const float* __restrict__ p,
    const float* __restrict__ q, const double* __restrict__ rho_it,
    const double* __restrict__ pq_it, double* __restrict__ rho_next) {
  int lane = threadIdx.x & 63;
  double rho = bfly_sum_d(rho_it[lane]);
  double pq = bfly_sum_d(pq_it[lane]);
  float alpha = (float)(rho / pq);
  double acc = 0.0;
  int stride = gridDim.x * blockDim.x;
  for (int i = blockIdx.x * blockDim.x + threadIdx.x; i < NN; i += stride) {
    x[i] = fmaf(alpha, p[i], x[i]);
    float rn = fmaf(-alpha, q[i], r[i]);
    r[i] = rn;
    acc += (double)rn * (double)rn;
  }
  __shared__ double sred[4];
  acc = wave_down_sum_d(acc);
  if ((threadIdx.x & 63) == 0) sred[threadIdx.x >> 6] = acc;
  __syncthreads();
  if (threadIdx.x == 0) rho_next[blockIdx.x] = sred[0] + sred[1] + sred[2] + sred[3];
}

__global__ __launch_bounds__(256) void cg_pupdate(
    float* __restrict__ p, const float* __restrict__ r,
    const double* __restrict__ rho_it, const double* __restrict__ rho_next) {
  int lane = threadIdx.x & 63;
  double r0 = bfly_sum_d(rho_it[lane]);
  double r1 = bfly_sum_d(rho_next[lane]);
  float beta = (float)(r1 / r0);
  int stride = gridDim.x * blockDim.x;
  for (int i = blockIdx.x * blockDim.x + threadIdx.x; i < NN; i += stride)
    p[i] = fmaf(beta, p[i], r[i]);
}

// ---------------- predict: out = K_test @ alpha, fused ----------------

__global__ __launch_bounds__(256) void predict(
    const float* __restrict__ Xte, const float* __restrict__ Xtr,
    const float* __restrict__ xx_te, const float* __restrict__ xx_tr,
    const float* __restrict__ alpha, float* __restrict__ out) {
  __shared__ float As[64][36];
  __shared__ float Bs[64][36];
  __shared__ float al[64];
  __shared__ float xxB[64];
  __shared__ double red[64][17];
  int i0 = blockIdx.x * 64;
  int tid = threadIdx.x;
  for (int t = tid; t < 64 * 32; t += 256) {
    int rr = t >> 5, cc = t & 31;
    As[rr][cc] = Xte[(size_t)(i0 + rr) * DD + cc];
  }
  int tx = tid & 15, ty = tid >> 4;
  float xxA[4];
#pragma unroll
  for (int u = 0; u < 4; ++u) xxA[u] = xx_te[i0 + ty * 4 + u];
  double accout[4] = {0.0, 0.0, 0.0, 0.0};
  for (int j0 = 0; j0 < NN; j0 += 64) {
    __syncthreads();
    for (int t = tid; t < 64 * 32; t += 256) {
      int rr = t >> 5, cc = t & 31;
      Bs[rr][cc] = Xtr[(size_t)(j0 + rr) * DD + cc];
    }
    if (tid < 64) {
      al[tid] = alpha[j0 + tid];
      xxB[tid] = xx_tr[j0 + tid];
    }
    __syncthreads();
    float dot[4][4] = {};
#pragma unroll
    for (int k = 0; k < 32; k += 4) {
      float4 a[4], b[4];
#pragma unroll
      for (int u = 0; u < 4; ++u) a[u] = *(const float4*)&As[ty * 4 + u][k];
#pragma unroll
      for (int v = 0; v < 4; ++v) b[v] = *(const float4*)&Bs[tx * 4 + v][k];
#pragma unroll
      for (int u = 0; u < 4; ++u)
#pragma unroll
        for (int v = 0; v < 4; ++v)
          dot[u][v] += a[u].x * b[v].x + a[u].y * b[v].y + a[u].z * b[v].z +
                       a[u].w * b[v].w;
    }
#pragma unroll
    for (int v = 0; v < 4; ++v) {
      float xxb = xxB[tx * 4 + v];
      float av = al[tx * 4 + v];
#pragma unroll
      for (int u = 0; u < 4; ++u) {
        float sq = fmaxf(xxA[u] + xxb - 2.0f * dot[u][v], 0.0f);
        accout[u] += (double)(expf(-GAMMA * sq) * av);
      }
    }
  }
  __syncthreads();
#pragma unroll
  for (int u = 0; u < 4; ++u) red[ty * 4 + u][tx] = accout[u];
  __syncthreads();
  if (tid < 64) {
    double s = 0.0;
#pragma unroll
    for (int t = 0; t < 16; ++t) s += red[tid][t];
    out[i0 + tid] = (float)s;
  }
}

// ---------------- launcher ----------------

extern "C" void kernel_launch(void* const* d_in, const int* in_sizes, int n_in,
                              void* d_out, int out_size, void* d_ws,
                              size_t ws_size, hipStream_t stream) {
  const float* X_train = (const float*)d_in[0];
  const float* y_train = (const float*)d_in[1];
  const float* X_test = (const float*)d_in[2];
  float* out = (float*)d_out;

  const size_t kbytes = (size_t)NN * NN * sizeof(float);  // 256MB
  const size_t small_bytes =
      6 * (size_t)NN * sizeof(float) +
      (size_t)NSLOT * (2 * NITER + 1) * sizeof(double) + 1024;

  // Path A needs K + small buffers (with slack); path B only small buffers.
  bool useK = (ws_size >= kbytes + (1 << 20));
  char* w = (char*)d_ws;
  float* Kbuf = (float*)w;
  size_t off = useK ? kbytes : 0;
  if (ws_size < off + small_bytes) {
    if (ws_size < small_bytes) return;  // hopeless; validation flags 0xAA
    useK = false;
    off = 0;
  }
  float* xx_tr = (float*)(w + off); off += NN * sizeof(float);
  float* xx_te = (float*)(w + off); off += NN * sizeof(float);
  float* xv = (float*)(w + off); off += NN * sizeof(float);
  float* rv = (float*)(w + off); off += NN * sizeof(float);
  float* pv = (float*)(w + off); off += NN * sizeof(float);
  float* qv = (float*)(w + off); off += NN * sizeof(float);
  off = (off + 255) & ~(size_t)255;
  double* rho = (double*)(w + off);
  off += (size_t)NSLOT * (NITER + 1) * sizeof(double);
  double* pq = (double*)(w + off);

  zero_accum<<<64, 256, 0, stream>>>(rho, NSLOT * (2 * NITER + 1));
  row_norms<<<NN / 256, 256, 0, stream>>>(X_train, xx_tr);
  row_norms<<<NN / 256, 256, 0, stream>>>(X_test, xx_te);
  cg_init<<<NSLOT, 256, 0, stream>>>(y_train, xv, rv, pv, rho);
  if (useK)
    build_K<<<dim3(NN / 64, NN / 64), 256, 0, stream>>>(X_train, xx_tr, Kbuf);

  for (int it = 0; it < NITER; ++it) {
    if (useK)
      matvec<<<NN, 256, 0, stream>>>(Kbuf, pv, qv, pq + (size_t)it * NSLOT);
    else
      matvec_free<<<NN / 64, 256, 0, stream>>>(X_train, xx_tr, pv, qv,
                                               pq + (size_t)it * NSLOT);
    cg_update<<<NSLOT, 256, 0, stream>>>(xv, rv, pv, qv,
                                         rho + (size_t)it * NSLOT,
                                         pq + (size_t)it * NSLOT,
                                         rho + (size_t)(it + 1) * NSLOT);
    cg_pupdate<<<NSLOT, 256, 0, stream>>>(pv, rv, rho + (size_t)it * NSLOT,
                                          rho + (size_t)(it + 1) * NSLOT);
  }

  predict<<<NN / 64, 256, 0, stream>>>(X_test, X_train, xx_te, xx_tr, xv, out);
}

// Round 3
// 18120.215 us; speedup vs baseline: 3.9940x; 3.9940x over previous
//
#include <hip/hip_runtime.h>

// Kernel ridge regression, RBF kernel. N=M=8192, D=32, gamma=1/32, reg=1e-3.
// Matrix-free CG: the gram operator is recomputed on the fly each matvec
// (A-rows cached in registers, B-tiles staged in LDS, fp64 accumulation).
// Grid-capture-safe: all CG scalars live in per-iteration fp64 slot arrays.
// 3 kernels per CG iteration: rbf_mv_part -> cg_update -> cg_pupdate.
// Output: same fused operator applied to (X_test, alpha).

#define NN 8192
#define DD 32
#define GAMMA 0.03125f
#define REGL 1e-3f
#define NITER 128
#define JS 8            // column slices per matvec
#define CPS (NN / JS)   // 1024 cols per slice -> 16 tiles of 64

__device__ __forceinline__ double bfly_sum_d(double v) {
#pragma unroll
  for (int off = 1; off < 64; off <<= 1) v += __shfl_xor(v, off, 64);
  return v;
}

__device__ __forceinline__ double wave_down_sum_d(double v) {
#pragma unroll
  for (int off = 32; off > 0; off >>= 1) v += __shfl_down(v, off, 64);
  return v;
}

// block-level reduce of one double into out[blockIdx.x] (256 threads)
__device__ __forceinline__ void block_reduce_store(double acc,
                                                   double* __restrict__ out) {
  __shared__ double sred[4];
  acc = wave_down_sum_d(acc);
  if ((threadIdx.x & 63) == 0) sred[threadIdx.x >> 6] = acc;
  __syncthreads();
  if (threadIdx.x == 0)
    out[blockIdx.x] = sred[0] + sred[1] + sred[2] + sred[3];
}

// ---------------- init ----------------

__global__ void zero_accum(double* __restrict__ buf, int n) {
  int stride = gridDim.x * blockDim.x;
  for (int i = blockIdx.x * blockDim.x + threadIdx.x; i < n; i += stride)
    buf[i] = 0.0;
}

__global__ void row_norms(const float* __restrict__ X, float* __restrict__ xx) {
  int i = blockIdx.x * blockDim.x + threadIdx.x;
  if (i < NN) {
    const float4* row = (const float4*)(X + (size_t)i * DD);
    float s = 0.f;
#pragma unroll
    for (int k = 0; k < DD / 4; ++k) {
      float4 v = row[k];
      s += v.x * v.x + v.y * v.y + v.z * v.z + v.w * v.w;
    }
    xx[i] = s;
  }
}

// grid 32 x 256 : one element per thread; rho0 and pp0 partials per block.
__global__ __launch_bounds__(256) void cg_init(const float* __restrict__ y,
                                               float* __restrict__ x,
                                               float* __restrict__ r,
                                               float* __restrict__ p,
                                               double* __restrict__ rho0,
                                               double* __restrict__ pp0) {
  int i = blockIdx.x * 256 + threadIdx.x;
  float v = y[i];
  x[i] = 0.f;
  r[i] = v;
  p[i] = v;
  double acc = (double)v * (double)v;
  __shared__ double sred[4];
  double w = wave_down_sum_d(acc);
  if ((threadIdx.x & 63) == 0) sred[threadIdx.x >> 6] = w;
  __syncthreads();
  if (threadIdx.x == 0) {
    double t = sred[0] + sred[1] + sred[2] + sred[3];
    rho0[blockIdx.x] = t;
    pp0[blockIdx.x] = t;  // p == y at iter 0
  }
}

// ---------------- fused RBF operator partial-matvec ----------------
// part[s][i] = sum_{j in slice s} exp(-g*||Xa_i - Xb_j||^2) * w[j]
// Grid: (NN/64 row tiles, JS slices), 256 threads as 16x16, 4x4 micro-tile.
// A rows live in registers (32 floats x 4 rows); B tiles staged in LDS.
// If pq_slots != nullptr, also atomically accumulates sum_i w[i]*part[s][i]
// (the p.(Kp) pieces for CG's alpha).

__global__ __launch_bounds__(256, 2) void rbf_mv_part(
    const float* __restrict__ Xa, const float* __restrict__ xxa,
    const float* __restrict__ Xb, const float* __restrict__ xxb,
    const float* __restrict__ w, float* __restrict__ part,
    double* __restrict__ pq_slots) {
  __shared__ float Bs[64][36];  // 144B rows: 16B-aligned, 2-way banks (free)
  __shared__ float wj[64];
  __shared__ float xxB[64];
  __shared__ double red[64][17];
  const int i0 = blockIdx.x * 64;
  const int s = blockIdx.y;
  const int tid = threadIdx.x;
  const int tx = tid & 15, ty = tid >> 4;

  // A fragment: rows i0 + ty*4 + u, all 32 k, in registers.
  float4 areg[4][8];
#pragma unroll
  for (int u = 0; u < 4; ++u) {
    const float4* row = (const float4*)(Xa + (size_t)(i0 + ty * 4 + u) * DD);
#pragma unroll
    for (int k = 0; k < 8; ++k) areg[u][k] = row[k];
  }
  float xxA[4];
#pragma unroll
  for (int u = 0; u < 4; ++u) xxA[u] = xxa[i0 + ty * 4 + u];

  double accq[4] = {0.0, 0.0, 0.0, 0.0};

  for (int t = 0; t < CPS / 64; ++t) {
    const int j0 = s * CPS + t * 64;
    __syncthreads();  // Bs/wj reuse guard
    for (int idx = tid; idx < 512; idx += 256) {
      int rr = idx >> 3, k4 = idx & 7;
      *(float4*)&Bs[rr][k4 * 4] =
          *(const float4*)(Xb + (size_t)(j0 + rr) * DD + k4 * 4);
    }
    if (tid < 64) {
      wj[tid] = w[j0 + tid];
      xxB[tid] = xxb[j0 + tid];
    }
    __syncthreads();

    float dot[4][4] = {};
#pragma unroll
    for (int kc = 0; kc < 8; ++kc) {
      float4 b[4];
#pragma unroll
      for (int v = 0; v < 4; ++v)
        b[v] = *(const float4*)&Bs[tx * 4 + v][kc * 4];
#pragma unroll
      for (int u = 0; u < 4; ++u) {
        float4 a = areg[u][kc];
#pragma unroll
        for (int v = 0; v < 4; ++v)
          dot[u][v] +=
              a.x * b[v].x + a.y * b[v].y + a.z * b[v].z + a.w * b[v].w;
      }
    }
#pragma unroll
    for (int v = 0; v < 4; ++v) {
      float xxb_v = xxB[tx * 4 + v];
      float wv = wj[tx * 4 + v];
#pragma unroll
      for (int u = 0; u < 4; ++u) {
        float sq = fmaxf(xxA[u] + xxb_v - 2.0f * dot[u][v], 0.0f);
        accq[u] += (double)(expf(-GAMMA * sq) * wv);  // accurate expf: K-entry
                                                      // errors amplify ~1e3x
                                                      // through the 1e-3 reg
      }
    }
  }

  __syncthreads();
#pragma unroll
  for (int u = 0; u < 4; ++u) red[ty * 4 + u][tx] = accq[u];
  __syncthreads();
  if (tid < 64) {
    double ssum = 0.0;
#pragma unroll
    for (int t2 = 0; t2 < 16; ++t2) ssum += red[tid][t2];
    part[(size_t)s * NN + i0 + tid] = (float)ssum;
    if (pq_slots) {
      double c = bfly_sum_d(ssum * (double)w[i0 + tid]);
      if (tid == 0)
        atomicAdd(&pq_slots[(blockIdx.x + (blockIdx.y << 7)) & 63], c);
    }
  }
}

// ---------------- CG updates ----------------
// grid 32 x 256, one element per thread.
// alpha = rho / (p.Kp + reg*p.p); q_i = sum_s qpart[s][i] + reg*p_i;
// x += alpha p; r -= alpha q; rho_next partials <- r.r

__global__ __launch_bounds__(256) void cg_update(
    float* __restrict__ x, float* __restrict__ r, const float* __restrict__ p,
    const float* __restrict__ qpart, const double* __restrict__ rho_it,
    const double* __restrict__ pq_it, const double* __restrict__ pp_it,
    double* __restrict__ rho_next) {
  int lane = threadIdx.x & 63;
  double rho = bfly_sum_d(rho_it[lane]);
  double pq = bfly_sum_d(pq_it[lane]);
  double pp = bfly_sum_d(pp_it[lane]);
  float alpha = (float)(rho / (pq + (double)REGL * pp));
  int i = blockIdx.x * 256 + threadIdx.x;
  float pi = p[i];
  double qs = 0.0;
#pragma unroll
  for (int s2 = 0; s2 < JS; ++s2) qs += (double)qpart[(size_t)s2 * NN + i];
  float qv = (float)(qs + (double)REGL * (double)pi);
  x[i] = fmaf(alpha, pi, x[i]);
  float rn = fmaf(-alpha, qv, r[i]);
  r[i] = rn;
  block_reduce_store((double)rn * (double)rn, rho_next);
}

// beta = rho_next/rho; p = r + beta p; pp_next partials <- p.p
__global__ __launch_bounds__(256) void cg_pupdate(
    float* __restrict__ p, const float* __restrict__ r,
    const double* __restrict__ rho_it, const double* __restrict__ rho_next,
    double* __restrict__ pp_next) {
  int lane = threadIdx.x & 63;
  double r0 = bfly_sum_d(rho_it[lane]);
  double r1 = bfly_sum_d(rho_next[lane]);
  float beta = (float)(r1 / r0);
  int i = blockIdx.x * 256 + threadIdx.x;
  float pn = fmaf(beta, p[i], r[i]);
  p[i] = pn;
  block_reduce_store((double)pn * (double)pn, pp_next);
}

// out[i] = sum_s opart[s][i]
__global__ __launch_bounds__(256) void reduce_out(
    const float* __restrict__ opart, float* __restrict__ out) {
  int i = blockIdx.x * 256 + threadIdx.x;
  double s = 0.0;
#pragma unroll
  for (int s2 = 0; s2 < JS; ++s2) s += (double)opart[(size_t)s2 * NN + i];
  out[i] = (float)s;
}

// ---------------- launcher ----------------

extern "C" void kernel_launch(void* const* d_in, const int* in_sizes, int n_in,
                              void* d_out, int out_size, void* d_ws,
                              size_t ws_size, hipStream_t stream) {
  const float* X_train = (const float*)d_in[0];
  const float* y_train = (const float*)d_in[1];
  const float* X_test = (const float*)d_in[2];
  float* out = (float*)d_out;

  char* w = (char*)d_ws;
  size_t off = 0;
  float* xx_tr = (float*)(w + off); off += NN * sizeof(float);
  float* xx_te = (float*)(w + off); off += NN * sizeof(float);
  float* xv = (float*)(w + off); off += NN * sizeof(float);
  float* rv = (float*)(w + off); off += NN * sizeof(float);
  float* pv = (float*)(w + off); off += NN * sizeof(float);
  float* qpart = (float*)(w + off); off += (size_t)JS * NN * sizeof(float);
  off = (off + 255) & ~(size_t)255;
  // slot arrays: rho[NITER+1][64], pq[NITER][64], pp[NITER+1][64]
  double* slots = (double*)(w + off);
  const int nslots = (3 * NITER + 2) * 64;
  off += (size_t)nslots * sizeof(double);
  if (ws_size < off) return;  // ~620KB needed; validation will flag 0xAA
  double* rho = slots;                         // (NITER+1)*64
  double* pq = slots + (size_t)(NITER + 1) * 64;  // NITER*64
  double* pp = pq + (size_t)NITER * 64;           // (NITER+1)*64

  zero_accum<<<64, 256, 0, stream>>>(slots, nslots);
  row_norms<<<NN / 256, 256, 0, stream>>>(X_train, xx_tr);
  row_norms<<<NN / 256, 256, 0, stream>>>(X_test, xx_te);
  cg_init<<<NN / 256, 256, 0, stream>>>(y_train, xv, rv, pv, rho, pp);

  for (int it = 0; it < NITER; ++it) {
    rbf_mv_part<<<dim3(NN / 64, JS), 256, 0, stream>>>(
        X_train, xx_tr, X_train, xx_tr, pv, qpart, pq + (size_t)it * 64);
    cg_update<<<NN / 256, 256, 0, stream>>>(
        xv, rv, pv, qpart, rho + (size_t)it * 64, pq + (size_t)it * 64,
        pp + (size_t)it * 64, rho + (size_t)(it + 1) * 64);
    cg_pupdate<<<NN / 256, 256, 0, stream>>>(
        pv, rv, rho + (size_t)it * 64, rho + (size_t)(it + 1) * 64,
        pp + (size_t)(it + 1) * 64);
  }

  // predict: opart (reuses qpart) = per-slice partials of K_test @ alpha
  rbf_mv_part<<<dim3(NN / 64, JS), 256, 0, stream>>>(
      X_test, xx_te, X_train, xx_tr, xv, qpart, nullptr);
  reduce_out<<<NN / 256, 256, 0, stream>>>(qpart, out);
}

// Round 4
// 6565.376 us; speedup vs baseline: 11.0232x; 2.7600x over previous
//
#include <hip/hip_runtime.h>

// Kernel ridge regression, RBF kernel. N=M=8192, D=32, gamma=1/32, reg=1e-3.
// Matrix-free CG with MFMA gram tiles: X split into bf16 hi+lo, dot = 3
// chained mfma_f32_16x16x32_bf16 (fp32-grade accuracy), exp epilogue in the
// MFMA C/D lane layout (col=lane&15, row=quad*4+reg). p-update fused into the
// matvec (beta from device slot arrays). 2 kernels per CG iteration.
// Graph-capture-safe: no host scalars, fixed launch sequence.

#define NN 8192
#define DD 32
#define REGL 1e-3f
#define NITER 128
#define JS 8
#define CPS (NN / JS)  // 1024 cols per slice -> 64 tiles of 16
#define NSLOT 32
// gamma*log2(e) = 1.4426950408889634/32
#define NC2 (-0.045084220027780106f)  // -gamma*log2e
#define C2P (0.09016844005556021f)    // +2*gamma*log2e

typedef short v8s __attribute__((ext_vector_type(8)));
typedef float v4f __attribute__((ext_vector_type(4)));

__device__ __forceinline__ ushort f2bf(float x) {  // RNE float->bf16 bits
  unsigned u = __float_as_uint(x);
  return (ushort)((u + 0x7fff + ((u >> 16) & 1)) >> 16);
}
__device__ __forceinline__ float bf2f(ushort b) {
  return __uint_as_float(((unsigned)b) << 16);
}

__device__ __forceinline__ double bfly64_d(double v) {
#pragma unroll
  for (int m = 1; m < 64; m <<= 1) v += __shfl_xor(v, m, 64);
  return v;
}
__device__ __forceinline__ double wave_down_sum_d(double v) {
#pragma unroll
  for (int off = 32; off > 0; off >>= 1) v += __shfl_down(v, off, 64);
  return v;
}
// sum of s[0..31]; valid in all lanes (each 32-half reduces its own copy)
__device__ __forceinline__ double slot_sum32(const double* __restrict__ s,
                                             int lane) {
  double v = s[lane & 31];
#pragma unroll
  for (int m = 1; m < 32; m <<= 1) v += __shfl_xor(v, m, 64);
  return v;
}
__device__ __forceinline__ void block_reduce_store(double acc,
                                                   double* __restrict__ out) {
  __shared__ double sred[4];
  acc = wave_down_sum_d(acc);
  if ((threadIdx.x & 63) == 0) sred[threadIdx.x >> 6] = acc;
  __syncthreads();
  if (threadIdx.x == 0)
    out[blockIdx.x] = sred[0] + sred[1] + sred[2] + sred[3];
}

// ---------------- init / precompute ----------------

__global__ void zero_accum(double* __restrict__ buf, int n) {
  int stride = gridDim.x * blockDim.x;
  for (int i = blockIdx.x * blockDim.x + threadIdx.x; i < n; i += stride)
    buf[i] = 0.0;
}

__global__ void row_norms(const float* __restrict__ X, float* __restrict__ xx) {
  int i = blockIdx.x * blockDim.x + threadIdx.x;
  if (i < NN) {
    const float4* row = (const float4*)(X + (size_t)i * DD);
    float s = 0.f;
#pragma unroll
    for (int k = 0; k < DD / 4; ++k) {
      float4 v = row[k];
      s += v.x * v.x + v.y * v.y + v.z * v.z + v.w * v.w;
    }
    xx[i] = s;
  }
}

// Swizzle X into MFMA fragment order, bf16 hi/lo planes.
// Per 16-row tile: 1024 ushorts = [64 lanes x 8 hi][64 lanes x 8 lo];
// lane l holds row tile*16+(l&15), k = 8*(l>>4)..+7.
__global__ __launch_bounds__(256) void make_frags(const float* __restrict__ X,
                                                  ushort* __restrict__ frag) {
  int t = blockIdx.x * 4 + (threadIdx.x >> 6);
  int lane = threadIdx.x & 63;
  int row = t * 16 + (lane & 15);
  int kb = (lane >> 4) * 8;
  const float4* rp = (const float4*)(X + (size_t)row * DD + kb);
  float4 f0 = rp[0], f1 = rp[1];
  float f[8] = {f0.x, f0.y, f0.z, f0.w, f1.x, f1.y, f1.z, f1.w};
  union {
    ushort u[8];
    uint4 q;
  } H, L;
#pragma unroll
  for (int j = 0; j < 8; ++j) {
    ushort hb = f2bf(f[j]);
    H.u[j] = hb;
    L.u[j] = f2bf(f[j] - bf2f(hb));
  }
  *(uint4*)(frag + (size_t)t * 1024 + lane * 8) = H.q;
  *(uint4*)(frag + (size_t)t * 1024 + 512 + lane * 8) = L.q;
}

// On-the-fly fragment conversion (small-workspace fallback path).
__device__ __forceinline__ void conv_frag(const float* __restrict__ X, int row,
                                          int kb, v8s& h, v8s& l) {
  const float4* rp = (const float4*)(X + (size_t)row * DD + kb);
  float4 f0 = rp[0], f1 = rp[1];
  float f[8] = {f0.x, f0.y, f0.z, f0.w, f1.x, f1.y, f1.z, f1.w};
  union {
    v8s v;
    ushort u[8];
  } H, L;
#pragma unroll
  for (int j = 0; j < 8; ++j) {
    ushort hb = f2bf(f[j]);
    H.u[j] = hb;
    L.u[j] = f2bf(f[j] - bf2f(hb));
  }
  h = H.v;
  l = L.v;
}

// grid 32 x 256: x=0, r=p=y; rho0 = pp0 = y.y partials
__global__ __launch_bounds__(256) void cg_init(const float* __restrict__ y,
                                               float* __restrict__ x,
                                               float* __restrict__ r,
                                               float* __restrict__ p,
                                               double* __restrict__ rho0,
                                               double* __restrict__ pp0) {
  int i = blockIdx.x * 256 + threadIdx.x;
  float v = y[i];
  x[i] = 0.f;
  r[i] = v;
  p[i] = v;
  __shared__ double sred[4];
  double acc = wave_down_sum_d((double)v * (double)v);
  if ((threadIdx.x & 63) == 0) sred[threadIdx.x >> 6] = acc;
  __syncthreads();
  if (threadIdx.x == 0) {
    double t = sred[0] + sred[1] + sred[2] + sred[3];
    rho0[blockIdx.x] = t;
    pp0[blockIdx.x] = t;
  }
}

// ---------------- fused RBF matvec (MFMA) ----------------
// qpart[s][i] = sum_{j in slice s} exp(-g||Xa_i - Xb_j||^2) * p_j
// with p_j = first ? p_old[j] : r[j] + beta*p_old[j]  (beta from rho slots).
// Slice-0 blocks persist p_new and accumulate pp; all blocks accumulate pq.
// Block = 4 waves, each wave one 16-row tile; wave loops over 16-col tiles.

template <bool HF>
__global__ __launch_bounds__(256) void rbf_mv(
    const float* __restrict__ Xa, const ushort* __restrict__ fragA,
    const float* __restrict__ xxa, const float* __restrict__ Xb,
    const ushort* __restrict__ fragB, const float* __restrict__ xxb,
    const float* __restrict__ rvec, const float* __restrict__ p_old,
    float* __restrict__ p_new, const double* __restrict__ rho_k,
    const double* __restrict__ rho_km1, int first, float* __restrict__ qpart,
    double* __restrict__ pq_slots, double* __restrict__ pp_slots) {
  const int tid = threadIdx.x;
  const int lane = tid & 63;
  const int n = lane & 15, q4 = lane >> 4;
  const int i0 = blockIdx.x * 64 + (tid >> 6) * 16;
  const int s = blockIdx.y;

  float beta = 0.f;
  if (!first) {
    double r1 = slot_sum32(rho_k, lane);
    double r0 = slot_sum32(rho_km1, lane);
    beta = (float)(r1 / r0);
  }

  v8s ah, al;
  if (HF) {
    const ushort* fa = fragA + (size_t)(i0 >> 4) * 1024 + lane * 8;
    ah = *(const v8s*)fa;
    al = *(const v8s*)(fa + 512);
  } else {
    conv_frag(Xa, i0 + n, q4 * 8, ah, al);
  }
  float nxA[4];
#pragma unroll
  for (int u = 0; u < 4; ++u) nxA[u] = NC2 * xxa[i0 + q4 * 4 + u];

  float racc[4] = {0.f, 0.f, 0.f, 0.f};

  for (int t = 0; t < CPS / 16; ++t) {
    const int j0 = s * CPS + t * 16;
    v8s bh, bl;
    if (HF) {
      const ushort* fb = fragB + (size_t)(j0 >> 4) * 1024 + lane * 8;
      bh = *(const v8s*)fb;
      bl = *(const v8s*)(fb + 512);
    } else {
      conv_frag(Xb, j0 + n, q4 * 8, bh, bl);
    }
    float wn =
        first ? p_old[j0 + n] : fmaf(beta, p_old[j0 + n], rvec[j0 + n]);
    float bu = NC2 * xxb[j0 + n];
    v4f c = {0.f, 0.f, 0.f, 0.f};
    c = __builtin_amdgcn_mfma_f32_16x16x32_bf16(al, bh, c, 0, 0, 0);
    c = __builtin_amdgcn_mfma_f32_16x16x32_bf16(ah, bl, c, 0, 0, 0);
    c = __builtin_amdgcn_mfma_f32_16x16x32_bf16(ah, bh, c, 0, 0, 0);
#pragma unroll
    for (int u = 0; u < 4; ++u) {
      float tt = fminf(fmaf(c[u], C2P, nxA[u] + bu), 0.f);
      racc[u] = fmaf(exp2f(tt), wn, racc[u]);  // v_exp_f32: ~1ulp; K rel err
                                               // ~1e-6, fp32-grade
    }
  }

  // reduce each row over the 16 col-lanes
#pragma unroll
  for (int u = 0; u < 4; ++u) {
#pragma unroll
    for (int m = 1; m < 16; m <<= 1) racc[u] += __shfl_xor(racc[u], m, 64);
  }

  const int writep = (pp_slots != nullptr) && (s == 0) && (!first);
  double cpq = 0.0, cpp = 0.0;
  if (n == 0) {
#pragma unroll
    for (int u = 0; u < 4; ++u) {
      int row = i0 + q4 * 4 + u;
      qpart[(size_t)s * NN + row] = racc[u];
      if (pq_slots) {
        float pnr =
            first ? p_old[row] : fmaf(beta, p_old[row], rvec[row]);
        cpq += (double)racc[u] * (double)pnr;
        if (writep) {
          p_new[row] = pnr;
          cpp += (double)pnr * (double)pnr;
        }
      }
    }
  }
  if (pq_slots) {
    cpq = bfly64_d(cpq);
    if (lane == 0)
      atomicAdd(&pq_slots[(blockIdx.x * 4 + (tid >> 6) + blockIdx.y) & 31],
                cpq);
    if (writep) {
      cpp = bfly64_d(cpp);
      if (lane == 0)
        atomicAdd(&pp_slots[(blockIdx.x * 4 + (tid >> 6)) & 31], cpp);
    }
  }
}

// ---------------- CG update (x, r, rho_next) ----------------

__global__ __launch_bounds__(256) void cg_update(
    float* __restrict__ x, float* __restrict__ r, const float* __restrict__ p,
    const float* __restrict__ qpart, const double* __restrict__ rho_k,
    const double* __restrict__ pq_k, const double* __restrict__ pp_k,
    double* __restrict__ rho_next) {
  int lane = threadIdx.x & 63;
  double rho = slot_sum32(rho_k, lane);
  double pq = slot_sum32(pq_k, lane);
  double pp = slot_sum32(pp_k, lane);
  float alpha = (float)(rho / (pq + (double)REGL * pp));
  int i = blockIdx.x * 256 + threadIdx.x;
  float pi = p[i];
  double qd = 0.0;
#pragma unroll
  for (int s2 = 0; s2 < JS; ++s2) qd += (double)qpart[(size_t)s2 * NN + i];
  float qv = (float)(qd + (double)REGL * (double)pi);
  x[i] = fmaf(alpha, pi, x[i]);
  float rn = fmaf(-alpha, qv, r[i]);
  r[i] = rn;
  block_reduce_store((double)rn * (double)rn, rho_next);
}

__global__ __launch_bounds__(256) void reduce_out(
    const float* __restrict__ opart, float* __restrict__ out) {
  int i = blockIdx.x * 256 + threadIdx.x;
  double s = 0.0;
#pragma unroll
  for (int s2 = 0; s2 < JS; ++s2) s += (double)opart[(size_t)s2 * NN + i];
  out[i] = (float)s;
}

// ---------------- launcher ----------------

extern "C" void kernel_launch(void* const* d_in, const int* in_sizes, int n_in,
                              void* d_out, int out_size, void* d_ws,
                              size_t ws_size, hipStream_t stream) {
  const float* X_train = (const float*)d_in[0];
  const float* y_train = (const float*)d_in[1];
  const float* X_test = (const float*)d_in[2];
  float* out = (float*)d_out;

  char* w = (char*)d_ws;
  size_t off = 0;
  float* xx_tr = (float*)(w + off); off += NN * 4;
  float* xx_te = (float*)(w + off); off += NN * 4;
  float* xv = (float*)(w + off); off += NN * 4;
  float* rv = (float*)(w + off); off += NN * 4;
  float* pA = (float*)(w + off); off += NN * 4;
  float* pB = (float*)(w + off); off += NN * 4;
  float* qpart = (float*)(w + off); off += (size_t)JS * NN * 4;
  off = (off + 255) & ~(size_t)255;
  double* rho = (double*)(w + off); off += (size_t)(NITER + 1) * NSLOT * 8;
  double* pq = (double*)(w + off); off += (size_t)NITER * NSLOT * 8;
  double* pp = (double*)(w + off); off += (size_t)(NITER + 1) * NSLOT * 8;
  // proven (R3 passed at 614KB): ws >= ~614KB >= 547KB small footprint
  if (ws_size < off) return;

  const size_t fragBytes = (size_t)(NN / 16) * 1024 * sizeof(ushort);  // 1MB
  off = (off + 255) & ~(size_t)255;
  bool HF = (ws_size >= off + 2 * fragBytes);
  ushort* fragTr = (ushort*)(w + off);
  ushort* fragTe = (ushort*)(w + off + fragBytes);

  const int nslots = (3 * NITER + 2) * NSLOT;
  zero_accum<<<64, 256, 0, stream>>>(rho, nslots);
  row_norms<<<NN / 256, 256, 0, stream>>>(X_train, xx_tr);
  row_norms<<<NN / 256, 256, 0, stream>>>(X_test, xx_te);
  if (HF) {
    make_frags<<<NN / 64, 256, 0, stream>>>(X_train, fragTr);
    make_frags<<<NN / 64, 256, 0, stream>>>(X_test, fragTe);
  }
  cg_init<<<NN / 256, 256, 0, stream>>>(y_train, xv, rv, pA, rho, pp);

  for (int it = 0; it < NITER; ++it) {
    float* pold = (it == 0) ? pA : ((it & 1) ? pA : pB);
    float* pnew = (it & 1) ? pB : pA;  // it0: pA==p0 already (no write)
    float* pcur = (it & 1) ? pB : pA;
    if (HF)
      rbf_mv<true><<<dim3(NN / 64, JS), 256, 0, stream>>>(
          X_train, fragTr, xx_tr, X_train, fragTr, xx_tr, rv, pold, pnew,
          rho + (size_t)it * NSLOT, rho + (size_t)(it ? it - 1 : 0) * NSLOT,
          (it == 0) ? 1 : 0, qpart, pq + (size_t)it * NSLOT,
          pp + (size_t)it * NSLOT);
    else
      rbf_mv<false><<<dim3(NN / 64, JS), 256, 0, stream>>>(
          X_train, nullptr, xx_tr, X_train, nullptr, xx_tr, rv, pold, pnew,
          rho + (size_t)it * NSLOT, rho + (size_t)(it ? it - 1 : 0) * NSLOT,
          (it == 0) ? 1 : 0, qpart, pq + (size_t)it * NSLOT,
          pp + (size_t)it * NSLOT);
    cg_update<<<NN / 256, 256, 0, stream>>>(
        xv, rv, pcur, qpart, rho + (size_t)it * NSLOT,
        pq + (size_t)it * NSLOT, pp + (size_t)it * NSLOT,
        rho + (size_t)(it + 1) * NSLOT);
  }

  // predict: out = K_test @ alpha (alpha = xv), fused, then slice-reduce
  if (HF)
    rbf_mv<true><<<dim3(NN / 64, JS), 256, 0, stream>>>(
        X_test, fragTe, xx_te, X_train, fragTr, xx_tr, rv, xv, nullptr, rho,
        rho, 1, qpart, nullptr, nullptr);
  else
    rbf_mv<false><<<dim3(NN / 64, JS), 256, 0, stream>>>(
        X_test, nullptr, xx_te, X_train, nullptr, xx_tr, rv, xv, nullptr, rho,
        rho, 1, qpart, nullptr, nullptr);
  reduce_out<<<NN / 256, 256, 0, stream>>>(qpart, out);
}

// Round 6
// 6197.673 us; speedup vs baseline: 11.6772x; 1.0593x over previous
//
#include <hip/hip_runtime.h>

// Kernel ridge regression, RBF kernel. N=M=8192, D=32, gamma=1/32, reg=1e-3.
// Matrix-free CG, MFMA gram tiles (bf16 hi/lo split, 3 chained MFMAs =
// fp32-grade dot). 32 rows/wave + LDS-staged B fragments shared by the
// block's 4 waves, JS=16 slices. NITER=128 (R5's 80 failed at absmax 0.070:
// the bf16 comparison floor at 128 iters masks true margin — do not cut).
// Graph-capture-safe: device-side fp64 slot arrays, fixed launch sequence.

#define NN 8192
#define DD 32
#define REGL 1e-3f
#define NITER 128
#define NSLOT 32
#define NC2 (-0.045084220027780106f)  // -gamma*log2e
#define C2P (0.09016844005556021f)    // +2*gamma*log2e

typedef short v8s __attribute__((ext_vector_type(8)));
typedef float v4f __attribute__((ext_vector_type(4)));

__device__ __forceinline__ ushort f2bf(float x) {  // RNE float->bf16 bits
  unsigned u = __float_as_uint(x);
  return (ushort)((u + 0x7fff + ((u >> 16) & 1)) >> 16);
}
__device__ __forceinline__ float bf2f(ushort b) {
  return __uint_as_float(((unsigned)b) << 16);
}

__device__ __forceinline__ double bfly64_d(double v) {
#pragma unroll
  for (int m = 1; m < 64; m <<= 1) v += __shfl_xor(v, m, 64);
  return v;
}
__device__ __forceinline__ double wave_down_sum_d(double v) {
#pragma unroll
  for (int off = 32; off > 0; off >>= 1) v += __shfl_down(v, off, 64);
  return v;
}
__device__ __forceinline__ double slot_sum32(const double* __restrict__ s,
                                             int lane) {
  double v = s[lane & 31];
#pragma unroll
  for (int m = 1; m < 32; m <<= 1) v += __shfl_xor(v, m, 64);
  return v;
}
__device__ __forceinline__ void block_reduce_store(double acc,
                                                   double* __restrict__ out) {
  __shared__ double sred[4];
  acc = wave_down_sum_d(acc);
  if ((threadIdx.x & 63) == 0) sred[threadIdx.x >> 6] = acc;
  __syncthreads();
  if (threadIdx.x == 0)
    out[blockIdx.x] = sred[0] + sred[1] + sred[2] + sred[3];
}

// ---------------- init / precompute ----------------

__global__ void zero_accum(double* __restrict__ buf, int n) {
  int stride = gridDim.x * blockDim.x;
  for (int i = blockIdx.x * blockDim.x + threadIdx.x; i < n; i += stride)
    buf[i] = 0.0;
}

__global__ void row_norms(const float* __restrict__ X, float* __restrict__ xx) {
  int i = blockIdx.x * blockDim.x + threadIdx.x;
  if (i < NN) {
    const float4* row = (const float4*)(X + (size_t)i * DD);
    float s = 0.f;
#pragma unroll
    for (int k = 0; k < DD / 4; ++k) {
      float4 v = row[k];
      s += v.x * v.x + v.y * v.y + v.z * v.z + v.w * v.w;
    }
    xx[i] = s;
  }
}

// Swizzle X into MFMA fragment order, bf16 hi/lo planes.
// Per 16-row tile: 1024 ushorts = [64 lanes x 8 hi][64 lanes x 8 lo];
// lane l holds row tile*16+(l&15), k = 8*(l>>4)..+7.
__global__ __launch_bounds__(256) void make_frags(const float* __restrict__ X,
                                                  ushort* __restrict__ frag) {
  int t = blockIdx.x * 4 + (threadIdx.x >> 6);
  int lane = threadIdx.x & 63;
  int row = t * 16 + (lane & 15);
  int kb = (lane >> 4) * 8;
  const float4* rp = (const float4*)(X + (size_t)row * DD + kb);
  float4 f0 = rp[0], f1 = rp[1];
  float f[8] = {f0.x, f0.y, f0.z, f0.w, f1.x, f1.y, f1.z, f1.w};
  union {
    ushort u[8];
    uint4 q;
  } H, L;
#pragma unroll
  for (int j = 0; j < 8; ++j) {
    ushort hb = f2bf(f[j]);
    H.u[j] = hb;
    L.u[j] = f2bf(f[j] - bf2f(hb));
  }
  *(uint4*)(frag + (size_t)t * 1024 + lane * 8) = H.q;
  *(uint4*)(frag + (size_t)t * 1024 + 512 + lane * 8) = L.q;
}

__device__ __forceinline__ void conv_frag(const float* __restrict__ X, int row,
                                          int kb, v8s& h, v8s& l) {
  const float4* rp = (const float4*)(X + (size_t)row * DD + kb);
  float4 f0 = rp[0], f1 = rp[1];
  float f[8] = {f0.x, f0.y, f0.z, f0.w, f1.x, f1.y, f1.z, f1.w};
  union {
    v8s v;
    ushort u[8];
  } H, L;
#pragma unroll
  for (int j = 0; j < 8; ++j) {
    ushort hb = f2bf(f[j]);
    H.u[j] = hb;
    L.u[j] = f2bf(f[j] - bf2f(hb));
  }
  h = H.v;
  l = L.v;
}

__global__ __launch_bounds__(256) void cg_init(const float* __restrict__ y,
                                               float* __restrict__ x,
                                               float* __restrict__ r,
                                               float* __restrict__ p,
                                               double* __restrict__ rho0,
                                               double* __restrict__ pp0) {
  int i = blockIdx.x * 256 + threadIdx.x;
  float v = y[i];
  x[i] = 0.f;
  r[i] = v;
  p[i] = v;
  __shared__ double sred[4];
  double acc = wave_down_sum_d((double)v * (double)v);
  if ((threadIdx.x & 63) == 0) sred[threadIdx.x >> 6] = acc;
  __syncthreads();
  if (threadIdx.x == 0) {
    double t = sred[0] + sred[1] + sred[2] + sred[3];
    rho0[blockIdx.x] = t;
    pp0[blockIdx.x] = t;
  }
}

// ---------------- fused RBF matvec (MFMA + LDS B-staging) ----------------
// qpart[s][i] = sum_{j in slice s} exp(-g||Xa_i - Xb_j||^2) * w_j,
// w_j = first ? p_old[j] : r[j] + beta*p_old[j]  (beta from rho slots).
// Block: 4 waves x 32 rows = 128 rows; B-tiles staged in LDS 4 at a time,
// shared by all waves. Slice-0 blocks persist p_new and accumulate p.p.

template <bool HF>
__global__ __launch_bounds__(256, 4) void rbf_mv(
    const float* __restrict__ Xa, const ushort* __restrict__ fragA,
    const float* __restrict__ xxa, const float* __restrict__ Xb,
    const ushort* __restrict__ fragB, const float* __restrict__ xxb,
    const float* __restrict__ rvec, const float* __restrict__ p_old,
    float* __restrict__ p_new, const double* __restrict__ rho_k,
    const double* __restrict__ rho_km1, int first, int js,
    float* __restrict__ qpart, double* __restrict__ pq_slots,
    double* __restrict__ pp_slots) {
  __shared__ __align__(16) ushort Bfrag[4][2][512];  // 4 tiles x hi/lo x 1KB
  __shared__ float Wj[4][16];   // staged weights (p-combined)
  __shared__ float XXj[4][16];  // staged NC2*xxb
  const int tid = threadIdx.x;
  const int lane = tid & 63;
  const int n = lane & 15, q4 = lane >> 4;
  const int wid = tid >> 6;
  const int i0 = blockIdx.x * 128 + wid * 32;  // 32 rows per wave
  const int s = blockIdx.y;
  const int CPSr = NN / js;
  const int rounds = CPSr / 64;  // 4 tiles of 16 per round

  float beta = 0.f;
  if (!first) {
    double r1 = slot_sum32(rho_k, lane);
    double r0 = slot_sum32(rho_km1, lane);
    beta = (float)(r1 / r0);
  }

  // two A fragment sets (rows i0..i0+15, i0+16..i0+31)
  v8s ah0, al0, ah1, al1;
  if (HF) {
    const ushort* fa = fragA + (size_t)(i0 >> 4) * 1024 + lane * 8;
    ah0 = *(const v8s*)fa;
    al0 = *(const v8s*)(fa + 512);
    ah1 = *(const v8s*)(fa + 1024);
    al1 = *(const v8s*)(fa + 1536);
  } else {
    conv_frag(Xa, i0 + n, q4 * 8, ah0, al0);
    conv_frag(Xa, i0 + 16 + n, q4 * 8, ah1, al1);
  }
  float nxA[2][4];
#pragma unroll
  for (int rt = 0; rt < 2; ++rt)
#pragma unroll
    for (int u = 0; u < 4; ++u)
      nxA[rt][u] = NC2 * xxa[i0 + rt * 16 + q4 * 4 + u];

  float racc[2][4] = {};

  for (int rd = 0; rd < rounds; ++rd) {
    __syncthreads();
    {  // stage 4 tiles (64 cols): each thread converts/copies one frag-lane
      int r = tid >> 6, l = tid & 63;
      int j0r = s * CPSr + (rd * 4 + r) * 16;
      if (HF) {
        const ushort* fb = fragB + (size_t)(j0r >> 4) * 1024 + l * 8;
        *(uint4*)&Bfrag[r][0][l * 8] = *(const uint4*)fb;
        *(uint4*)&Bfrag[r][1][l * 8] = *(const uint4*)(fb + 512);
      } else {
        v8s h, lo;
        conv_frag(Xb, j0r + (l & 15), (l >> 4) * 8, h, lo);
        *(v8s*)&Bfrag[r][0][l * 8] = h;
        *(v8s*)&Bfrag[r][1][l * 8] = lo;
      }
      if (tid < 64) {
        int r2 = tid >> 4, idx = tid & 15;
        int j = s * CPSr + (rd * 4 + r2) * 16 + idx;
        float pv = p_old[j];
        Wj[r2][idx] = first ? pv : fmaf(beta, pv, rvec[j]);
        XXj[r2][idx] = NC2 * xxb[j];
      }
    }
    __syncthreads();
#pragma unroll
    for (int r = 0; r < 4; ++r) {
      v8s bh = *(const v8s*)&Bfrag[r][0][lane * 8];
      v8s bl = *(const v8s*)&Bfrag[r][1][lane * 8];
      float wn = Wj[r][n];
      float bu = XXj[r][n];
      v4f c0 = {0.f, 0.f, 0.f, 0.f}, c1 = {0.f, 0.f, 0.f, 0.f};
      c0 = __builtin_amdgcn_mfma_f32_16x16x32_bf16(al0, bh, c0, 0, 0, 0);
      c0 = __builtin_amdgcn_mfma_f32_16x16x32_bf16(ah0, bl, c0, 0, 0, 0);
      c0 = __builtin_amdgcn_mfma_f32_16x16x32_bf16(ah0, bh, c0, 0, 0, 0);
      c1 = __builtin_amdgcn_mfma_f32_16x16x32_bf16(al1, bh, c1, 0, 0, 0);
      c1 = __builtin_amdgcn_mfma_f32_16x16x32_bf16(ah1, bl, c1, 0, 0, 0);
      c1 = __builtin_amdgcn_mfma_f32_16x16x32_bf16(ah1, bh, c1, 0, 0, 0);
#pragma unroll
      for (int u = 0; u < 4; ++u) {
        float t0 = fminf(fmaf(c0[u], C2P, nxA[0][u] + bu), 0.f);
        racc[0][u] = fmaf(exp2f(t0), wn, racc[0][u]);
        float t1 = fminf(fmaf(c1[u], C2P, nxA[1][u] + bu), 0.f);
        racc[1][u] = fmaf(exp2f(t1), wn, racc[1][u]);
      }
    }
  }

  // reduce rows over the 16 col-lanes (C/D layout: col = lane&15)
#pragma unroll
  for (int rt = 0; rt < 2; ++rt)
#pragma unroll
    for (int u = 0; u < 4; ++u) {
#pragma unroll
      for (int m = 1; m < 16; m <<= 1)
        racc[rt][u] += __shfl_xor(racc[rt][u], m, 64);
    }

  const int writep = (pp_slots != nullptr) && (s == 0) && (!first);
  double cpq = 0.0, cpp = 0.0;
  if (n == 0) {
#pragma unroll
    for (int rt = 0; rt < 2; ++rt)
#pragma unroll
      for (int u = 0; u < 4; ++u) {
        int row = i0 + rt * 16 + q4 * 4 + u;
        qpart[(size_t)s * NN + row] = racc[rt][u];
        if (pq_slots) {
          float pnr = first ? p_old[row] : fmaf(beta, p_old[row], rvec[row]);
          cpq += (double)racc[rt][u] * (double)pnr;
          if (writep) {
            p_new[row] = pnr;
            cpp += (double)pnr * (double)pnr;
          }
        }
      }
  }
  if (pq_slots) {
    cpq = bfly64_d(cpq);
    if (lane == 0)
      atomicAdd(&pq_slots[(blockIdx.x * 4 + wid + blockIdx.y) & 31], cpq);
    if (writep) {
      cpp = bfly64_d(cpp);
      if (lane == 0) atomicAdd(&pp_slots[(blockIdx.x * 4 + wid) & 31], cpp);
    }
  }
}

// ---------------- CG update (x, r, rho_next) ----------------

__global__ __launch_bounds__(256) void cg_update(
    float* __restrict__ x, float* __restrict__ r, const float* __restrict__ p,
    const float* __restrict__ qpart, const double* __restrict__ rho_k,
    const double* __restrict__ pq_k, const double* __restrict__ pp_k,
    double* __restrict__ rho_next, int js) {
  int lane = threadIdx.x & 63;
  double rho = slot_sum32(rho_k, lane);
  double pq = slot_sum32(pq_k, lane);
  double pp = slot_sum32(pp_k, lane);
  float alpha = (float)(rho / (pq + (double)REGL * pp));
  int i = blockIdx.x * 256 + threadIdx.x;
  float pi = p[i];
  double qd = 0.0;
  for (int s2 = 0; s2 < js; ++s2) qd += (double)qpart[(size_t)s2 * NN + i];
  float qv = (float)(qd + (double)REGL * (double)pi);
  x[i] = fmaf(alpha, pi, x[i]);
  float rn = fmaf(-alpha, qv, r[i]);
  r[i] = rn;
  block_reduce_store((double)rn * (double)rn, rho_next);
}

__global__ __launch_bounds__(256) void reduce_out(
    const float* __restrict__ opart, float* __restrict__ out, int js) {
  int i = blockIdx.x * 256 + threadIdx.x;
  double s = 0.0;
  for (int s2 = 0; s2 < js; ++s2) s += (double)opart[(size_t)s2 * NN + i];
  out[i] = (float)s;
}

// ---------------- launcher ----------------

extern "C" void kernel_launch(void* const* d_in, const int* in_sizes, int n_in,
                              void* d_out, int out_size, void* d_ws,
                              size_t ws_size, hipStream_t stream) {
  const float* X_train = (const float*)d_in[0];
  const float* y_train = (const float*)d_in[1];
  const float* X_test = (const float*)d_in[2];
  float* out = (float*)d_out;

  const size_t fragBytes = (size_t)(NN / 16) * 1024 * sizeof(ushort);  // 1MB
  const int nslots = (3 * NITER + 2) * NSLOT;
  // footprint(js) = 6 vecs + qpart(js) + slots (+256 align slack)
  auto footprint = [&](int js) {
    return (size_t)6 * NN * 4 + (size_t)js * NN * 4 + 512 +
           (size_t)nslots * 8;
  };
  int js;
  bool HF;
  if (ws_size >= footprint(16) + 2 * fragBytes + 256) {
    js = 16; HF = true;
  } else if (ws_size >= footprint(16)) {
    js = 16; HF = false;
  } else if (ws_size >= footprint(8)) {
    js = 8; HF = false;  // proven available (R3 ran at ~614KB need)
  } else {
    return;
  }

  char* w = (char*)d_ws;
  size_t off = 0;
  float* xx_tr = (float*)(w + off); off += NN * 4;
  float* xx_te = (float*)(w + off); off += NN * 4;
  float* xv = (float*)(w + off); off += NN * 4;
  float* rv = (float*)(w + off); off += NN * 4;
  float* pA = (float*)(w + off); off += NN * 4;
  float* pB = (float*)(w + off); off += NN * 4;
  float* qpart = (float*)(w + off); off += (size_t)js * NN * 4;
  off = (off + 255) & ~(size_t)255;
  double* rho = (double*)(w + off); off += (size_t)(NITER + 1) * NSLOT * 8;
  double* pq = (double*)(w + off); off += (size_t)NITER * NSLOT * 8;
  double* pp = (double*)(w + off); off += (size_t)(NITER + 1) * NSLOT * 8;
  off = (off + 255) & ~(size_t)255;
  ushort* fragTr = (ushort*)(w + off);
  ushort* fragTe = (ushort*)(w + off + fragBytes);

  zero_accum<<<64, 256, 0, stream>>>(rho, nslots);
  row_norms<<<NN / 256, 256, 0, stream>>>(X_train, xx_tr);
  row_norms<<<NN / 256, 256, 0, stream>>>(X_test, xx_te);
  if (HF) {
    make_frags<<<NN / 64, 256, 0, stream>>>(X_train, fragTr);
    make_frags<<<NN / 64, 256, 0, stream>>>(X_test, fragTe);
  }
  cg_init<<<NN / 256, 256, 0, stream>>>(y_train, xv, rv, pA, rho, pp);

  dim3 mvgrid(NN / 128, js);
  for (int it = 0; it < NITER; ++it) {
    float* pold = (it & 1) ? pA : ((it == 0) ? pA : pB);
    float* pnew = (it & 1) ? pB : pA;
    float* pcur = (it & 1) ? pB : pA;
    if (it == 0) pcur = pA;
    if (HF)
      rbf_mv<true><<<mvgrid, 256, 0, stream>>>(
          X_train, fragTr, xx_tr, X_train, fragTr, xx_tr, rv, pold, pnew,
          rho + (size_t)it * NSLOT, rho + (size_t)(it ? it - 1 : 0) * NSLOT,
          (it == 0) ? 1 : 0, js, qpart, pq + (size_t)it * NSLOT,
          pp + (size_t)it * NSLOT);
    else
      rbf_mv<false><<<mvgrid, 256, 0, stream>>>(
          X_train, nullptr, xx_tr, X_train, nullptr, xx_tr, rv, pold, pnew,
          rho + (size_t)it * NSLOT, rho + (size_t)(it ? it - 1 : 0) * NSLOT,
          (it == 0) ? 1 : 0, js, qpart, pq + (size_t)it * NSLOT,
          pp + (size_t)it * NSLOT);
    cg_update<<<NN / 256, 256, 0, stream>>>(
        xv, rv, pcur, qpart, rho + (size_t)it * NSLOT,
        pq + (size_t)it * NSLOT, pp + (size_t)it * NSLOT,
        rho + (size_t)(it + 1) * NSLOT, js);
  }

  // predict: out = K_test @ alpha (alpha = xv)
  if (HF)
    rbf_mv<true><<<mvgrid, 256, 0, stream>>>(
        X_test, fragTe, xx_te, X_train, fragTr, xx_tr, rv, xv, nullptr, rho,
        rho, 1, js, qpart, nullptr, nullptr);
  else
    rbf_mv<false><<<mvgrid, 256, 0, stream>>>(
        X_test, nullptr, xx_te, X_train, nullptr, xx_tr, rv, xv, nullptr, rho,
        rho, 1, js, qpart, nullptr, nullptr);
  reduce_out<<<NN / 256, 256, 0, stream>>>(qpart, out, js);
}

// Round 7
// 5911.521 us; speedup vs baseline: 12.2425x; 1.0484x over previous
//
#include <hip/hip_runtime.h>

// Kernel ridge regression, RBF kernel. N=M=8192, D=32, gamma=1/32, reg=1e-3.
// Matrix-free CG, MFMA gram tiles (bf16 hi/lo split, 3 chained MFMAs =
// fp32-grade dot). R7: hardware v_exp_f32 (libm exp2f was a ~50-op software
// routine = the R4/R6 bottleneck) + norm terms folded into the MFMA
// accumulator init (fragments pre-scaled by sqrt(2*gamma*log2e)).
// NITER=128 (R5's 80 failed at 0.070 — bf16 floor masks margin; do not cut).
// Graph-capture-safe: device-side fp64 slot arrays, fixed launch sequence.

#define NN 8192
#define DD 32
#define REGL 1e-3f
#define NITER 128
#define NSLOT 32
#define NC2 (-0.045084220027780106f)  // -gamma*log2e
#define SCF (0.3002806023f)           // sqrt(2*gamma*log2e); dot of scaled
                                      // frags = 2*gamma*log2e * x.y

typedef short v8s __attribute__((ext_vector_type(8)));
typedef float v4f __attribute__((ext_vector_type(4)));

__device__ __forceinline__ float fast_exp2(float x) {
#if __has_builtin(__builtin_amdgcn_exp2f)
  return __builtin_amdgcn_exp2f(x);  // v_exp_f32, ~1 ulp
#else
  float r;
  asm("v_exp_f32 %0, %1" : "=v"(r) : "v"(x));
  return r;
#endif
}

__device__ __forceinline__ ushort f2bf(float x) {  // RNE float->bf16 bits
  unsigned u = __float_as_uint(x);
  return (ushort)((u + 0x7fff + ((u >> 16) & 1)) >> 16);
}
__device__ __forceinline__ float bf2f(ushort b) {
  return __uint_as_float(((unsigned)b) << 16);
}

__device__ __forceinline__ double bfly64_d(double v) {
#pragma unroll
  for (int m = 1; m < 64; m <<= 1) v += __shfl_xor(v, m, 64);
  return v;
}
__device__ __forceinline__ double wave_down_sum_d(double v) {
#pragma unroll
  for (int off = 32; off > 0; off >>= 1) v += __shfl_down(v, off, 64);
  return v;
}
__device__ __forceinline__ double slot_sum32(const double* __restrict__ s,
                                             int lane) {
  double v = s[lane & 31];
#pragma unroll
  for (int m = 1; m < 32; m <<= 1) v += __shfl_xor(v, m, 64);
  return v;
}
__device__ __forceinline__ void block_reduce_store(double acc,
                                                   double* __restrict__ out) {
  __shared__ double sred[4];
  acc = wave_down_sum_d(acc);
  if ((threadIdx.x & 63) == 0) sred[threadIdx.x >> 6] = acc;
  __syncthreads();
  if (threadIdx.x == 0)
    out[blockIdx.x] = sred[0] + sred[1] + sred[2] + sred[3];
}

// ---------------- init / precompute ----------------

__global__ void zero_accum(double* __restrict__ buf, int n) {
  int stride = gridDim.x * blockDim.x;
  for (int i = blockIdx.x * blockDim.x + threadIdx.x; i < n; i += stride)
    buf[i] = 0.0;
}

// stores NC2 * ||x||^2 (pre-scaled for the exp argument)
__global__ void row_norms(const float* __restrict__ X, float* __restrict__ xx) {
  int i = blockIdx.x * blockDim.x + threadIdx.x;
  if (i < NN) {
    const float4* row = (const float4*)(X + (size_t)i * DD);
    float s = 0.f;
#pragma unroll
    for (int k = 0; k < DD / 4; ++k) {
      float4 v = row[k];
      s += v.x * v.x + v.y * v.y + v.z * v.z + v.w * v.w;
    }
    xx[i] = NC2 * s;
  }
}

// Swizzle X into MFMA fragment order, bf16 hi/lo planes, scaled by SCF.
// Per 16-row tile: 1024 ushorts = [64 lanes x 8 hi][64 lanes x 8 lo];
// lane l holds row tile*16+(l&15), k = 8*(l>>4)..+7.
__global__ __launch_bounds__(256) void make_frags(const float* __restrict__ X,
                                                  ushort* __restrict__ frag) {
  int t = blockIdx.x * 4 + (threadIdx.x >> 6);
  int lane = threadIdx.x & 63;
  int row = t * 16 + (lane & 15);
  int kb = (lane >> 4) * 8;
  const float4* rp = (const float4*)(X + (size_t)row * DD + kb);
  float4 f0 = rp[0], f1 = rp[1];
  float f[8] = {f0.x, f0.y, f0.z, f0.w, f1.x, f1.y, f1.z, f1.w};
  union {
    ushort u[8];
    uint4 q;
  } H, L;
#pragma unroll
  for (int j = 0; j < 8; ++j) {
    float fs = SCF * f[j];
    ushort hb = f2bf(fs);
    H.u[j] = hb;
    L.u[j] = f2bf(fs - bf2f(hb));
  }
  *(uint4*)(frag + (size_t)t * 1024 + lane * 8) = H.q;
  *(uint4*)(frag + (size_t)t * 1024 + 512 + lane * 8) = L.q;
}

__device__ __forceinline__ void conv_frag(const float* __restrict__ X, int row,
                                          int kb, v8s& h, v8s& l) {
  const float4* rp = (const float4*)(X + (size_t)row * DD + kb);
  float4 f0 = rp[0], f1 = rp[1];
  float f[8] = {f0.x, f0.y, f0.z, f0.w, f1.x, f1.y, f1.z, f1.w};
  union {
    v8s v;
    ushort u[8];
  } H, L;
#pragma unroll
  for (int j = 0; j < 8; ++j) {
    float fs = SCF * f[j];
    ushort hb = f2bf(fs);
    H.u[j] = hb;
    L.u[j] = f2bf(fs - bf2f(hb));
  }
  h = H.v;
  l = L.v;
}

__global__ __launch_bounds__(256) void cg_init(const float* __restrict__ y,
                                               float* __restrict__ x,
                                               float* __restrict__ r,
                                               float* __restrict__ p,
                                               double* __restrict__ rho0,
                                               double* __restrict__ pp0) {
  int i = blockIdx.x * 256 + threadIdx.x;
  float v = y[i];
  x[i] = 0.f;
  r[i] = v;
  p[i] = v;
  __shared__ double sred[4];
  double acc = wave_down_sum_d((double)v * (double)v);
  if ((threadIdx.x & 63) == 0) sred[threadIdx.x >> 6] = acc;
  __syncthreads();
  if (threadIdx.x == 0) {
    double t = sred[0] + sred[1] + sred[2] + sred[3];
    rho0[blockIdx.x] = t;
    pp0[blockIdx.x] = t;
  }
}

// ---------------- fused RBF matvec (MFMA + LDS B-staging) ----------------
// qpart[s][i] = sum_{j in slice s} exp(-g||Xa_i - Xb_j||^2) * w_j,
// w_j = first ? p_old[j] : r[j] + beta*p_old[j]  (beta from rho slots).
// Block: 4 waves x 32 rows = 128 rows; B-tiles staged in LDS 4 at a time.
// MFMA C init = NC2*(xxA+xxB); D accumulates the scaled dot; epilogue is
// v_min + v_exp + v_fma per entry. Slice-0 blocks persist p_new / p.p.

template <bool HF>
__global__ __launch_bounds__(256, 4) void rbf_mv(
    const float* __restrict__ Xa, const ushort* __restrict__ fragA,
    const float* __restrict__ xxa, const float* __restrict__ Xb,
    const ushort* __restrict__ fragB, const float* __restrict__ xxb,
    const float* __restrict__ rvec, const float* __restrict__ p_old,
    float* __restrict__ p_new, const double* __restrict__ rho_k,
    const double* __restrict__ rho_km1, int first, int js,
    float* __restrict__ qpart, double* __restrict__ pq_slots,
    double* __restrict__ pp_slots) {
  __shared__ __align__(16) ushort Bfrag[4][2][512];  // 4 tiles x hi/lo x 1KB
  __shared__ float Wj[4][16];   // staged weights (p-combined)
  __shared__ float XXj[4][16];  // staged NC2*xxb
  const int tid = threadIdx.x;
  const int lane = tid & 63;
  const int n = lane & 15, q4 = lane >> 4;
  const int wid = tid >> 6;
  const int i0 = blockIdx.x * 128 + wid * 32;  // 32 rows per wave
  const int s = blockIdx.y;
  const int CPSr = NN / js;
  const int rounds = CPSr / 64;  // 4 tiles of 16 per round

  float beta = 0.f;
  if (!first) {
    double r1 = slot_sum32(rho_k, lane);
    double r0 = slot_sum32(rho_km1, lane);
    beta = (float)(r1 / r0);
  }

  // two A fragment sets (rows i0..i0+15, i0+16..i0+31)
  v8s ah0, al0, ah1, al1;
  if (HF) {
    const ushort* fa = fragA + (size_t)(i0 >> 4) * 1024 + lane * 8;
    ah0 = *(const v8s*)fa;
    al0 = *(const v8s*)(fa + 512);
    ah1 = *(const v8s*)(fa + 1024);
    al1 = *(const v8s*)(fa + 1536);
  } else {
    conv_frag(Xa, i0 + n, q4 * 8, ah0, al0);
    conv_frag(Xa, i0 + 16 + n, q4 * 8, ah1, al1);
  }
  float nxA[2][4];  // NC2*||xa||^2 (xxa pre-scaled)
#pragma unroll
  for (int rt = 0; rt < 2; ++rt)
#pragma unroll
    for (int u = 0; u < 4; ++u)
      nxA[rt][u] = xxa[i0 + rt * 16 + q4 * 4 + u];

  float racc[2][4] = {};

  for (int rd = 0; rd < rounds; ++rd) {
    __syncthreads();
    {  // stage 4 tiles (64 cols)
      int r = tid >> 6, l = tid & 63;
      int j0r = s * CPSr + (rd * 4 + r) * 16;
      if (HF) {
        const ushort* fb = fragB + (size_t)(j0r >> 4) * 1024 + l * 8;
        *(uint4*)&Bfrag[r][0][l * 8] = *(const uint4*)fb;
        *(uint4*)&Bfrag[r][1][l * 8] = *(const uint4*)(fb + 512);
      } else {
        v8s h, lo;
        conv_frag(Xb, j0r + (l & 15), (l >> 4) * 8, h, lo);
        *(v8s*)&Bfrag[r][0][l * 8] = h;
        *(v8s*)&Bfrag[r][1][l * 8] = lo;
      }
      if (tid < 64) {
        int r2 = tid >> 4, idx = tid & 15;
        int j = s * CPSr + (rd * 4 + r2) * 16 + idx;
        float pv = p_old[j];
        Wj[r2][idx] = first ? pv : fmaf(beta, pv, rvec[j]);
        XXj[r2][idx] = xxb[j];  // pre-scaled NC2*||xb||^2
      }
    }
    __syncthreads();
#pragma unroll
    for (int r = 0; r < 4; ++r) {
      v8s bh = *(const v8s*)&Bfrag[r][0][lane * 8];
      v8s bl = *(const v8s*)&Bfrag[r][1][lane * 8];
      float wn = Wj[r][n];
      float bu = XXj[r][n];
      v4f c0, c1;
#pragma unroll
      for (int u = 0; u < 4; ++u) {
        c0[u] = nxA[0][u] + bu;  // C-init carries the norm terms
        c1[u] = nxA[1][u] + bu;
      }
      c0 = __builtin_amdgcn_mfma_f32_16x16x32_bf16(al0, bh, c0, 0, 0, 0);
      c0 = __builtin_amdgcn_mfma_f32_16x16x32_bf16(ah0, bl, c0, 0, 0, 0);
      c0 = __builtin_amdgcn_mfma_f32_16x16x32_bf16(ah0, bh, c0, 0, 0, 0);
      c1 = __builtin_amdgcn_mfma_f32_16x16x32_bf16(al1, bh, c1, 0, 0, 0);
      c1 = __builtin_amdgcn_mfma_f32_16x16x32_bf16(ah1, bl, c1, 0, 0, 0);
      c1 = __builtin_amdgcn_mfma_f32_16x16x32_bf16(ah1, bh, c1, 0, 0, 0);
#pragma unroll
      for (int u = 0; u < 4; ++u) {
        racc[0][u] = fmaf(fast_exp2(fminf(c0[u], 0.f)), wn, racc[0][u]);
        racc[1][u] = fmaf(fast_exp2(fminf(c1[u], 0.f)), wn, racc[1][u]);
      }
    }
  }

  // reduce rows over the 16 col-lanes (C/D layout: col = lane&15)
#pragma unroll
  for (int rt = 0; rt < 2; ++rt)
#pragma unroll
    for (int u = 0; u < 4; ++u) {
#pragma unroll
      for (int m = 1; m < 16; m <<= 1)
        racc[rt][u] += __shfl_xor(racc[rt][u], m, 64);
    }

  const int writep = (pp_slots != nullptr) && (s == 0) && (!first);
  double cpq = 0.0, cpp = 0.0;
  if (n == 0) {
#pragma unroll
    for (int rt = 0; rt < 2; ++rt)
#pragma unroll
      for (int u = 0; u < 4; ++u) {
        int row = i0 + rt * 16 + q4 * 4 + u;
        qpart[(size_t)s * NN + row] = racc[rt][u];
        if (pq_slots) {
          float pnr = first ? p_old[row] : fmaf(beta, p_old[row], rvec[row]);
          cpq += (double)racc[rt][u] * (double)pnr;
          if (writep) {
            p_new[row] = pnr;
            cpp += (double)pnr * (double)pnr;
          }
        }
      }
  }
  if (pq_slots) {
    cpq = bfly64_d(cpq);
    if (lane == 0)
      atomicAdd(&pq_slots[(blockIdx.x * 4 + wid + blockIdx.y) & 31], cpq);
    if (writep) {
      cpp = bfly64_d(cpp);
      if (lane == 0) atomicAdd(&pp_slots[(blockIdx.x * 4 + wid) & 31], cpp);
    }
  }
}

// ---------------- CG update (x, r, rho_next) ----------------

__global__ __launch_bounds__(256) void cg_update(
    float* __restrict__ x, float* __restrict__ r, const float* __restrict__ p,
    const float* __restrict__ qpart, const double* __restrict__ rho_k,
    const double* __restrict__ pq_k, const double* __restrict__ pp_k,
    double* __restrict__ rho_next, int js) {
  int lane = threadIdx.x & 63;
  double rho = slot_sum32(rho_k, lane);
  double pq = slot_sum32(pq_k, lane);
  double pp = slot_sum32(pp_k, lane);
  float alpha = (float)(rho / (pq + (double)REGL * pp));
  int i = blockIdx.x * 256 + threadIdx.x;
  float pi = p[i];
  double qd = 0.0;
  for (int s2 = 0; s2 < js; ++s2) qd += (double)qpart[(size_t)s2 * NN + i];
  float qv = (float)(qd + (double)REGL * (double)pi);
  x[i] = fmaf(alpha, pi, x[i]);
  float rn = fmaf(-alpha, qv, r[i]);
  r[i] = rn;
  block_reduce_store((double)rn * (double)rn, rho_next);
}

__global__ __launch_bounds__(256) void reduce_out(
    const float* __restrict__ opart, float* __restrict__ out, int js) {
  int i = blockIdx.x * 256 + threadIdx.x;
  double s = 0.0;
  for (int s2 = 0; s2 < js; ++s2) s += (double)opart[(size_t)s2 * NN + i];
  out[i] = (float)s;
}

// ---------------- launcher ----------------

extern "C" void kernel_launch(void* const* d_in, const int* in_sizes, int n_in,
                              void* d_out, int out_size, void* d_ws,
                              size_t ws_size, hipStream_t stream) {
  const float* X_train = (const float*)d_in[0];
  const float* y_train = (const float*)d_in[1];
  const float* X_test = (const float*)d_in[2];
  float* out = (float*)d_out;

  const size_t fragBytes = (size_t)(NN / 16) * 1024 * sizeof(ushort);  // 1MB
  const int nslots = (3 * NITER + 2) * NSLOT;
  auto footprint = [&](int js) {
    return (size_t)6 * NN * 4 + (size_t)js * NN * 4 + 512 +
           (size_t)nslots * 8;
  };
  int js;
  bool HF;
  if (ws_size >= footprint(16) + 2 * fragBytes + 256) {
    js = 16; HF = true;
  } else if (ws_size >= footprint(16)) {
    js = 16; HF = false;
  } else if (ws_size >= footprint(8)) {
    js = 8; HF = false;
  } else {
    return;
  }

  char* w = (char*)d_ws;
  size_t off = 0;
  float* xx_tr = (float*)(w + off); off += NN * 4;
  float* xx_te = (float*)(w + off); off += NN * 4;
  float* xv = (float*)(w + off); off += NN * 4;
  float* rv = (float*)(w + off); off += NN * 4;
  float* pA = (float*)(w + off); off += NN * 4;
  float* pB = (float*)(w + off); off += NN * 4;
  float* qpart = (float*)(w + off); off += (size_t)js * NN * 4;
  off = (off + 255) & ~(size_t)255;
  double* rho = (double*)(w + off); off += (size_t)(NITER + 1) * NSLOT * 8;
  double* pq = (double*)(w + off); off += (size_t)NITER * NSLOT * 8;
  double* pp = (double*)(w + off); off += (size_t)(NITER + 1) * NSLOT * 8;
  off = (off + 255) & ~(size_t)255;
  ushort* fragTr = (ushort*)(w + off);
  ushort* fragTe = (ushort*)(w + off + fragBytes);

  zero_accum<<<64, 256, 0, stream>>>(rho, nslots);
  row_norms<<<NN / 256, 256, 0, stream>>>(X_train, xx_tr);
  row_norms<<<NN / 256, 256, 0, stream>>>(X_test, xx_te);
  if (HF) {
    make_frags<<<NN / 64, 256, 0, stream>>>(X_train, fragTr);
    make_frags<<<NN / 64, 256, 0, stream>>>(X_test, fragTe);
  }
  cg_init<<<NN / 256, 256, 0, stream>>>(y_train, xv, rv, pA, rho, pp);

  dim3 mvgrid(NN / 128, js);
  for (int it = 0; it < NITER; ++it) {
    float* pold = (it & 1) ? pA : ((it == 0) ? pA : pB);
    float* pnew = (it & 1) ? pB : pA;
    float* pcur = (it & 1) ? pB : pA;
    if (it == 0) pcur = pA;
    if (HF)
      rbf_mv<true><<<mvgrid, 256, 0, stream>>>(
          X_train, fragTr, xx_tr, X_train, fragTr, xx_tr, rv, pold, pnew,
          rho + (size_t)it * NSLOT, rho + (size_t)(it ? it - 1 : 0) * NSLOT,
          (it == 0) ? 1 : 0, js, qpart, pq + (size_t)it * NSLOT,
          pp + (size_t)it * NSLOT);
    else
      rbf_mv<false><<<mvgrid, 256, 0, stream>>>(
          X_train, nullptr, xx_tr, X_train, nullptr, xx_tr, rv, pold, pnew,
          rho + (size_t)it * NSLOT, rho + (size_t)(it ? it - 1 : 0) * NSLOT,
          (it == 0) ? 1 : 0, js, qpart, pq + (size_t)it * NSLOT,
          pp + (size_t)it * NSLOT);
    cg_update<<<NN / 256, 256, 0, stream>>>(
        xv, rv, pcur, qpart, rho + (size_t)it * NSLOT,
        pq + (size_t)it * NSLOT, pp + (size_t)it * NSLOT,
        rho + (size_t)(it + 1) * NSLOT, js);
  }

  // predict: out = K_test @ alpha (alpha = xv)
  if (HF)
    rbf_mv<true><<<mvgrid, 256, 0, stream>>>(
        X_test, fragTe, xx_te, X_train, fragTr, xx_tr, rv, xv, nullptr, rho,
        rho, 1, js, qpart, nullptr, nullptr);
  else
    rbf_mv<false><<<mvgrid, 256, 0, stream>>>(
        X_test, nullptr, xx_te, X_train, nullptr, xx_tr, rv, xv, nullptr, rho,
        rho, 1, js, qpart, nullptr, nullptr);
  reduce_out<<<NN / 256, 256, 0, stream>>>(qpart, out, js);
}